// Round 1
// baseline (5089.605 us; speedup 1.0000x reference)
//
#include <hip/hip_runtime.h>
#include <math.h>

#define BS 32
#define T 64
#define F 32
#define H 256
#define G4 1024
#define YIN 10

__device__ __forceinline__ float sigm(float x) { return 1.f / (1.f + expf(-x)); }

// ---------------------------------------------------------------------------
// k_scan: blocks 0..255 = feature LSTMs (s = bid>>7, f = (bid>>2)&31, bg = bid&3,
//         8 batches per block). blocks 256..263 = Y-LSTM (4 batches per block).
// Per step: gate dots (thread = gate column, 8|4 batch accumulators), LDS
// exchange, per-(b,n) state update. h broadcast from LDS as float4.
// ---------------------------------------------------------------------------
__global__ __launch_bounds__(1024) void k_scan(
    const float* __restrict__ Xp, const float* __restrict__ Xn,
    const float* __restrict__ Wxp, const float* __restrict__ Uxp, const float* __restrict__ bxp,
    const float* __restrict__ Wxn, const float* __restrict__ Uxn, const float* __restrict__ bxn,
    const float* __restrict__ Yin, const float* __restrict__ Wy,
    const float* __restrict__ Uy, const float* __restrict__ by,
    float* __restrict__ Yh, float* __restrict__ Ph, float* __restrict__ Nh)
{
  __shared__ __align__(16) float smem[8 * H + 8 * G4];  // 40 KB
  const int tid = threadIdx.x;
  const int bid = blockIdx.x;

  if (bid < 256) {
    // ---------------- feature LSTM block ----------------
    const int s  = bid >> 7;
    const int f  = (bid >> 2) & 31;
    const int bg = bid & 3;
    const float* X  = s ? Xn : Xp;
    const float* W  = s ? Wxn : Wxp;
    const float* U  = (s ? Uxn : Uxp) + (size_t)f * H * G4;
    const float* bb = s ? bxn : bxp;
    float* Acc = s ? Nh : Ph;

    float (*h_lds)[H]  = (float(*)[H])smem;             // [8][256]
    float (*g_lds)[G4] = (float(*)[G4])(smem + 8 * H);  // [8][1024]

    const float wj = W[f * G4 + tid];
    const float bj = bb[f * G4 + tid];
    const int n    = tid & 255;
    const int bsel = tid >> 8;  // 0..3 -> owns batches 2*bsel, 2*bsel+1
    float c0 = 0.f, c1 = 0.f;

    smem[tid] = 0.f; smem[tid + 1024] = 0.f;  // zero h_lds (2048 floats)
    __syncthreads();

    for (int t = 0; t < T; ++t) {
      float acc[8];
      #pragma unroll
      for (int b = 0; b < 8; ++b)
        acc[b] = X[(size_t)(bg * 8 + b) * (T * F) + t * F + f] * wj + bj;

      for (int k = 0; k < H; k += 4) {
        const float u0 = U[(k + 0) * G4 + tid];
        const float u1 = U[(k + 1) * G4 + tid];
        const float u2 = U[(k + 2) * G4 + tid];
        const float u3 = U[(k + 3) * G4 + tid];
        #pragma unroll
        for (int b = 0; b < 8; ++b) {
          const float4 hv = *(const float4*)&h_lds[b][k];
          acc[b] += u0 * hv.x + u1 * hv.y + u2 * hv.z + u3 * hv.w;
        }
      }
      #pragma unroll
      for (int b = 0; b < 8; ++b) g_lds[b][tid] = acc[b];
      __syncthreads();

      #pragma unroll
      for (int q = 0; q < 2; ++q) {
        const int b = bsel * 2 + q;
        const float ig = sigm(g_lds[b][n]);
        const float fg = sigm(g_lds[b][H + n]);
        const float gg = tanhf(g_lds[b][2 * H + n]);
        const float og = sigm(g_lds[b][3 * H + n]);
        float c = q ? c1 : c0;
        c = fg * c + ig * gg;
        if (q) c1 = c; else c0 = c;
        const float h = og * tanhf(c);
        h_lds[b][n] = h;
        atomicAdd(&Acc[(size_t)(bg * 8 + b) * (T * H) + t * H + n], h * (1.f / 32.f));
      }
      __syncthreads();
    }
  } else {
    // ---------------- Y-stream LSTM block ----------------
    const int yb = bid - 256;  // 0..7, batches yb*4..+4
    float (*h_lds)[H]  = (float(*)[H])smem;             // [4][256]
    float (*g_lds)[G4] = (float(*)[G4])(smem + 4 * H);  // [4][1024]

    float wy[YIN];
    #pragma unroll
    for (int i = 0; i < YIN; ++i) wy[i] = Wy[i * G4 + tid];
    const float bj = by[tid];
    const int n    = tid & 255;
    const int bsel = tid >> 8;  // batch within group
    float cc = 0.f;

    smem[tid] = 0.f;  // zero h_lds (1024 floats)
    __syncthreads();

    for (int t = 0; t < T; ++t) {
      float acc[4];
      #pragma unroll
      for (int b = 0; b < 4; ++b) {
        const float* yrow = Yin + (size_t)(yb * 4 + b) * (T * YIN) + t * YIN;
        float a = bj;
        #pragma unroll
        for (int i = 0; i < YIN; ++i) a += yrow[i] * wy[i];
        acc[b] = a;
      }
      for (int k = 0; k < H; k += 4) {
        const float u0 = Uy[(k + 0) * G4 + tid];
        const float u1 = Uy[(k + 1) * G4 + tid];
        const float u2 = Uy[(k + 2) * G4 + tid];
        const float u3 = Uy[(k + 3) * G4 + tid];
        #pragma unroll
        for (int b = 0; b < 4; ++b) {
          const float4 hv = *(const float4*)&h_lds[b][k];
          acc[b] += u0 * hv.x + u1 * hv.y + u2 * hv.z + u3 * hv.w;
        }
      }
      #pragma unroll
      for (int b = 0; b < 4; ++b) g_lds[b][tid] = acc[b];
      __syncthreads();

      {
        const int b = bsel;
        const float ig = sigm(g_lds[b][n]);
        const float fg = sigm(g_lds[b][H + n]);
        const float gg = tanhf(g_lds[b][2 * H + n]);
        const float og = sigm(g_lds[b][3 * H + n]);
        cc = fg * cc + ig * gg;
        const float h = og * tanhf(cc);
        h_lds[b][n] = h;
        Yh[(size_t)(yb * 4 + b) * (T * H) + t * H + n] = h;
      }
      __syncthreads();
    }
  }
}

// ---------------------------------------------------------------------------
// k_xg: MI-LSTM input projections. yg = Yh@Wm+bm, pg = Ph@Wpa+bpa,
// ng = Nh@Wna+bna. 8 (b,t)-rows per block staged in LDS.
// ---------------------------------------------------------------------------
__global__ __launch_bounds__(1024) void k_xg(
    const float* __restrict__ Yh, const float* __restrict__ Ph, const float* __restrict__ Nh,
    const float* __restrict__ Wm, const float* __restrict__ bm,
    const float* __restrict__ Wpa, const float* __restrict__ bpa,
    const float* __restrict__ Wna, const float* __restrict__ bna,
    float* __restrict__ yg, float* __restrict__ pg, float* __restrict__ ng)
{
  __shared__ __align__(16) float A[8][768];  // [row][Yh | Ph | Nh]
  const int tid = threadIdx.x;
  const int ro  = blockIdx.x * 8;

  for (int idx = tid; idx < 8 * 768; idx += 1024) {
    const int r = idx / 768, c = idx % 768;
    const int row = ro + r;
    float v;
    if (c < 256)      v = Yh[(size_t)row * H + c];
    else if (c < 512) v = Ph[(size_t)row * H + (c - 256)];
    else              v = Nh[(size_t)row * H + (c - 512)];
    A[r][c] = v;
  }
  __syncthreads();

  float acc[8];
  #pragma unroll
  for (int r = 0; r < 8; ++r) acc[r] = bm[tid];
  for (int k = 0; k < H; k += 4) {
    const float w0 = Wm[(k + 0) * G4 + tid];
    const float w1 = Wm[(k + 1) * G4 + tid];
    const float w2 = Wm[(k + 2) * G4 + tid];
    const float w3 = Wm[(k + 3) * G4 + tid];
    #pragma unroll
    for (int r = 0; r < 8; ++r) {
      const float4 av = *(const float4*)&A[r][k];
      acc[r] += w0 * av.x + w1 * av.y + w2 * av.z + w3 * av.w;
    }
  }
  #pragma unroll
  for (int r = 0; r < 8; ++r) yg[(size_t)(ro + r) * G4 + tid] = acc[r];

  const int col = tid & 511;
  const float* Wx = (tid < 512) ? Wpa : Wna;
  const float* bx = (tid < 512) ? bpa : bna;
  float* outp     = (tid < 512) ? pg : ng;
  const int aoff  = (tid < 512) ? 256 : 512;
  #pragma unroll
  for (int r = 0; r < 8; ++r) acc[r] = bx[col];
  for (int k = 0; k < H; k += 4) {
    const float w0 = Wx[(k + 0) * 512 + col];
    const float w1 = Wx[(k + 1) * 512 + col];
    const float w2 = Wx[(k + 2) * 512 + col];
    const float w3 = Wx[(k + 3) * 512 + col];
    #pragma unroll
    for (int r = 0; r < 8; ++r) {
      const float4 av = *(const float4*)&A[r][aoff + k];
      acc[r] += w0 * av.x + w1 * av.y + w2 * av.z + w3 * av.w;
    }
  }
  #pragma unroll
  for (int r = 0; r < 8; ++r) outp[(size_t)(ro + r) * 512 + col] = acc[r];
}

// ---------------------------------------------------------------------------
// k_mi: MI-LSTM scan, one block per batch element. Per step: recurrent dots
// (Um col tid; Upa/Una col; Wa attention col), LDS exchange, cell-attention
// softmax over 3 candidates via wave reduction, state update.
// ---------------------------------------------------------------------------
__global__ __launch_bounds__(1024) void k_mi(
    const float* __restrict__ yg, const float* __restrict__ pg, const float* __restrict__ ng,
    const float* __restrict__ Um, const float* __restrict__ Upa, const float* __restrict__ Una,
    const float* __restrict__ Wa, const float* __restrict__ ba,
    float* __restrict__ Hm)
{
  __shared__ __align__(16) float h_lds[H];
  __shared__ __align__(16) float c_lds[H];
  __shared__ float g_lds[G4];
  __shared__ float ga_lds[G4];   // [gp(512) | gn(512)]
  __shared__ float att_lds[H];
  __shared__ float red[3][4];
  const int tid = threadIdx.x;
  const int b   = blockIdx.x;

  if (tid < H) { h_lds[tid] = 0.f; c_lds[tid] = 0.f; }
  __syncthreads();

  for (int t = 0; t < T; ++t) {
    const size_t row = (size_t)b * T + t;

    float gacc = yg[row * G4 + tid];
    for (int k = 0; k < H; k += 4) {
      const float4 hv = *(const float4*)&h_lds[k];
      gacc += Um[(k + 0) * G4 + tid] * hv.x + Um[(k + 1) * G4 + tid] * hv.y
            + Um[(k + 2) * G4 + tid] * hv.z + Um[(k + 3) * G4 + tid] * hv.w;
    }

    const int acol = tid & 511;
    const float* Ux = (tid < 512) ? Upa : Una;
    float aacc = (tid < 512) ? pg[row * 512 + acol] : ng[row * 512 + acol];
    for (int k = 0; k < H; k += 4) {
      const float4 hv = *(const float4*)&h_lds[k];
      aacc += Ux[(k + 0) * 512 + acol] * hv.x + Ux[(k + 1) * 512 + acol] * hv.y
            + Ux[(k + 2) * 512 + acol] * hv.z + Ux[(k + 3) * 512 + acol] * hv.w;
    }

    float attv = 0.f;
    if (tid < H) {
      attv = ba[tid];
      for (int k = 0; k < H; k += 4) {
        const float4 cv = *(const float4*)&c_lds[k];
        attv += Wa[(k + 0) * H + tid] * cv.x + Wa[(k + 1) * H + tid] * cv.y
              + Wa[(k + 2) * H + tid] * cv.z + Wa[(k + 3) * H + tid] * cv.w;
      }
      attv = tanhf(attv);
    }

    g_lds[tid]  = gacc;
    ga_lds[tid] = aacc;
    if (tid < H) att_lds[tid] = attv;
    __syncthreads();

    float l0 = 0.f, l1 = 0.f, l2 = 0.f, fg = 0.f, og = 0.f;
    if (tid < H) {
      const int n = tid;
      const float ig = sigm(g_lds[n]);
      fg = sigm(g_lds[H + n]);
      const float gy = tanhf(g_lds[2 * H + n]);
      og = sigm(g_lds[3 * H + n]);
      l0 = ig * gy;
      l1 = sigm(ga_lds[n])         * tanhf(ga_lds[H + n]);
      l2 = sigm(ga_lds[2 * H + n]) * tanhf(ga_lds[3 * H + n]);
      const float a = att_lds[n];
      float v0 = l0 * a, v1 = l1 * a, v2 = l2 * a;
      for (int off = 32; off; off >>= 1) {
        v0 += __shfl_down(v0, off);
        v1 += __shfl_down(v1, off);
        v2 += __shfl_down(v2, off);
      }
      if ((tid & 63) == 0) {
        red[0][tid >> 6] = v0; red[1][tid >> 6] = v1; red[2][tid >> 6] = v2;
      }
    }
    __syncthreads();

    if (tid < H) {
      const int n = tid;
      const float s0 = red[0][0] + red[0][1] + red[0][2] + red[0][3];
      const float s1 = red[1][0] + red[1][1] + red[1][2] + red[1][3];
      const float s2 = red[2][0] + red[2][1] + red[2][2] + red[2][3];
      const float m  = fmaxf(s0, fmaxf(s1, s2));
      const float e0 = expf(s0 - m), e1 = expf(s1 - m), e2 = expf(s2 - m);
      const float inv = 1.f / (e0 + e1 + e2);
      const float lt  = (e0 * l0 + e1 * l1 + e2 * l2) * inv;
      const float c   = fg * c_lds[n] + lt;
      const float h   = og * tanhf(c);
      c_lds[n] = c;
      h_lds[n] = h;
      Hm[row * H + n] = h;
    }
    __syncthreads();
  }
}

// ---------------------------------------------------------------------------
// k_att: temporal additive attention + linear head. One block per batch.
// ---------------------------------------------------------------------------
__global__ __launch_bounds__(256) void k_att(
    const float* __restrict__ Hm, const float* __restrict__ Watt, const float* __restrict__ batt,
    const float* __restrict__ vatt, const float* __restrict__ Wlin, const float* __restrict__ blin,
    float* __restrict__ out)
{
  __shared__ __align__(16) float hm8[8][H];
  __shared__ float vred[8][4];
  __shared__ float s_lds[T];
  __shared__ float alpha_lds[T];
  __shared__ float red4[4];
  const int n = threadIdx.x;
  const int b = blockIdx.x;
  const float bn = batt[n], vn = vatt[n];

  for (int t0 = 0; t0 < T; t0 += 8) {
    __syncthreads();
    #pragma unroll
    for (int r = 0; r < 8; ++r) hm8[r][n] = Hm[((size_t)b * T + t0 + r) * H + n];
    __syncthreads();
    float acc[8];
    #pragma unroll
    for (int r = 0; r < 8; ++r) acc[r] = bn;
    for (int k = 0; k < H; k += 4) {
      const float w0 = Watt[(k + 0) * H + n];
      const float w1 = Watt[(k + 1) * H + n];
      const float w2 = Watt[(k + 2) * H + n];
      const float w3 = Watt[(k + 3) * H + n];
      #pragma unroll
      for (int r = 0; r < 8; ++r) {
        const float4 hv = *(const float4*)&hm8[r][k];
        acc[r] += w0 * hv.x + w1 * hv.y + w2 * hv.z + w3 * hv.w;
      }
    }
    #pragma unroll
    for (int r = 0; r < 8; ++r) {
      float v = tanhf(acc[r]) * vn;
      for (int off = 32; off; off >>= 1) v += __shfl_down(v, off);
      if ((n & 63) == 0) vred[r][n >> 6] = v;
    }
    __syncthreads();
    if (n < 8) s_lds[t0 + n] = vred[n][0] + vred[n][1] + vred[n][2] + vred[n][3];
  }
  __syncthreads();

  if (n < T) {
    const float sv = s_lds[n];
    float m = sv;
    for (int off = 32; off; off >>= 1) m = fmaxf(m, __shfl_xor(m, off));
    const float e = expf(sv - m);
    float sum = e;
    for (int off = 32; off; off >>= 1) sum += __shfl_xor(sum, off);
    alpha_lds[n] = e / sum;
  }
  __syncthreads();

  float acc = 0.f;
  for (int t = 0; t < T; ++t) acc += alpha_lds[t] * Hm[((size_t)b * T + t) * H + n];
  float p = acc * Wlin[n];
  for (int off = 32; off; off >>= 1) p += __shfl_down(p, off);
  if ((n & 63) == 0) red4[n >> 6] = p;
  __syncthreads();
  if (n == 0) out[b] = fmaxf(red4[0] + red4[1] + red4[2] + red4[3] + blin[0], 0.f);
}

// ---------------------------------------------------------------------------
extern "C" void kernel_launch(void* const* d_in, const int* in_sizes, int n_in,
                              void* d_out, int out_size, void* d_ws, size_t ws_size,
                              hipStream_t stream) {
  const float* Yin  = (const float*)d_in[0];
  const float* Xp   = (const float*)d_in[1];
  const float* Xn   = (const float*)d_in[2];
  const float* Wy   = (const float*)d_in[3];
  const float* Uy   = (const float*)d_in[4];
  const float* by   = (const float*)d_in[5];
  const float* Wxp  = (const float*)d_in[6];
  const float* Uxp  = (const float*)d_in[7];
  const float* bxp  = (const float*)d_in[8];
  const float* Wxn  = (const float*)d_in[9];
  const float* Uxn  = (const float*)d_in[10];
  const float* bxn  = (const float*)d_in[11];
  const float* Wm   = (const float*)d_in[12];
  const float* Um   = (const float*)d_in[13];
  const float* bm   = (const float*)d_in[14];
  const float* Wpa  = (const float*)d_in[15];
  const float* Upa  = (const float*)d_in[16];
  const float* bpa  = (const float*)d_in[17];
  const float* Wna  = (const float*)d_in[18];
  const float* Una  = (const float*)d_in[19];
  const float* bna  = (const float*)d_in[20];
  const float* Wa   = (const float*)d_in[21];
  const float* ba   = (const float*)d_in[22];
  const float* Watt = (const float*)d_in[23];
  const float* batt = (const float*)d_in[24];
  const float* vatt = (const float*)d_in[25];
  const float* Wlin = (const float*)d_in[26];
  const float* blin = (const float*)d_in[27];

  float* ws = (float*)d_ws;
  float* Yh = ws;                 // 32*64*256
  float* Ph = ws + 524288;        // 32*64*256
  float* Nh = ws + 1048576;       // 32*64*256
  float* Hm = ws + 1572864;       // 32*64*256
  float* yg = ws + 2097152;       // 32*64*1024
  float* pg = ws + 4194304;       // 32*64*512
  float* ng = ws + 5242880;       // 32*64*512
  float* out = (float*)d_out;

  // zero the feature-mean accumulators (Ph, Nh)
  hipMemsetAsync(Ph, 0, (size_t)2 * 524288 * sizeof(float), stream);

  k_scan<<<264, 1024, 0, stream>>>(Xp, Xn, Wxp, Uxp, bxp, Wxn, Uxn, bxn,
                                   Yin, Wy, Uy, by, Yh, Ph, Nh);
  k_xg<<<256, 1024, 0, stream>>>(Yh, Ph, Nh, Wm, bm, Wpa, bpa, Wna, bna, yg, pg, ng);
  k_mi<<<32, 1024, 0, stream>>>(yg, pg, ng, Um, Upa, Una, Wa, ba, Hm);
  k_att<<<32, 256, 0, stream>>>(Hm, Watt, batt, vatt, Wlin, blin, out);
}

// Round 2
// 2215.840 us; speedup vs baseline: 2.2969x; 2.2969x over previous
//
#include <hip/hip_runtime.h>
#include <math.h>

#define BS 32
#define T 64
#define F 32
#define H 256
#define G4 1024
#define YIN 10

typedef _Float16 f16;
typedef _Float16 f16x8 __attribute__((ext_vector_type(8)));
typedef float f32x4 __attribute__((ext_vector_type(4)));

__device__ __forceinline__ float sigm(float x) { return 1.f / (1.f + expf(-x)); }

// ---------------------------------------------------------------------------
// k_prep_u: frag-order U matrices into f16 for the persistent-register MFMA
// scan. Slot 0..31 = Uxp features, 32..63 = Uxn features, 64 = Uy.
// Fragment layout (per slot): [w(8)][nt(8)][kt(8)][lane(64)][e(8)] f16 where
//   B[k][col16]: k = kt*32 + (lane>>4)*8 + e, col = g*256 + w*32 + (nt&1)*16
//   + (lane&15), g = nt>>1.  (mfma_f32_16x16x32_f16 B-fragment order)
// ---------------------------------------------------------------------------
__global__ __launch_bounds__(512) void k_prep_u(
    const float* __restrict__ Uxp, const float* __restrict__ Uxn,
    const float* __restrict__ Uy, f16* __restrict__ Uf)
{
  const int slot = blockIdx.x;
  const float* src = (slot < 32) ? (Uxp + (size_t)slot * 262144)
                   : (slot < 64) ? (Uxn + (size_t)(slot - 32) * 262144)
                   : Uy;
  f16* dst = Uf + (size_t)slot * 262144;
  const int lane = threadIdx.x & 63;
  const int kt   = threadIdx.x >> 6;
  const int cl = lane & 15, lq = lane >> 4;
  for (int w = 0; w < 8; ++w)
    for (int nt = 0; nt < 8; ++nt) {
      const int g   = nt >> 1;
      const int col = g * 256 + w * 32 + (nt & 1) * 16 + cl;
      const int k0  = kt * 32 + lq * 8;
      f16x8 v;
      #pragma unroll
      for (int e = 0; e < 8; ++e) v[e] = (f16)src[(size_t)(k0 + e) * G4 + col];
      *(f16x8*)(dst + ((size_t)((w * 8 + nt) * 8 + kt) * 64 + lane) * 8) = v;
    }
}

// ---------------------------------------------------------------------------
// k_prep_w: flat f32 -> f16 conversion for the MI-LSTM weights.
// ---------------------------------------------------------------------------
__global__ __launch_bounds__(1024) void k_prep_w(
    const float* __restrict__ Um, const float* __restrict__ Upa,
    const float* __restrict__ Una, const float* __restrict__ Wa,
    f16* __restrict__ Umh, f16* __restrict__ Uph, f16* __restrict__ Unh,
    f16* __restrict__ Wah)
{
  const int i = blockIdx.x * 1024 + threadIdx.x;   // grid covers 262144
  Umh[i] = (f16)Um[i];
  if (i < 131072) { Uph[i] = (f16)Upa[i]; Unh[i] = (f16)Una[i]; }
  if (i < 65536)  Wah[i] = (f16)Wa[i];
}

// ---------------------------------------------------------------------------
// k_prep_yg0: yg0[b*T+t][col] = Y[b,t,:] @ Wy + by  (Y-LSTM input projection)
// ---------------------------------------------------------------------------
__global__ __launch_bounds__(1024) void k_prep_yg0(
    const float* __restrict__ Y, const float* __restrict__ Wy,
    const float* __restrict__ by, float* __restrict__ yg0)
{
  const int col = threadIdx.x;
  const int r0  = blockIdx.x * 16;
  float wv[YIN];
  #pragma unroll
  for (int i = 0; i < YIN; ++i) wv[i] = Wy[i * G4 + col];
  const float bv = by[col];
  for (int r = r0; r < r0 + 16; ++r) {
    float a = bv;
    #pragma unroll
    for (int i = 0; i < YIN; ++i) a += Y[r * YIN + i] * wv[i];
    yg0[(size_t)r * G4 + col] = a;
  }
}

// ---------------------------------------------------------------------------
// k_scan: persistent-weight MFMA LSTM scan.
// Blocks 0..127: feature LSTMs {s = b>>6, f = (b>>1)&31, bh = b&1 (16 batches)}.
// Blocks 128..129: Y-LSTM (bh = b&1).
// 512 threads = 8 waves. Wave w holds U columns {g*256 + w*32 + [0,32)} for all
// 4 gates as 64 f16x8 B-fragments in registers (loaded once). Per step:
//   h fragments (f16, LDS, A-layout) -> 64 MFMA -> gates in-register ->
//   state update -> write h back to LDS frag layout; atomicAdd feature mean.
// ---------------------------------------------------------------------------
__global__ __launch_bounds__(512, 1) void k_scan(
    const float* __restrict__ Xp, const float* __restrict__ Xn,
    const float* __restrict__ Wxp, const float* __restrict__ bxp,
    const float* __restrict__ Wxn, const float* __restrict__ bxn,
    const f16*  __restrict__ Uf,  const float* __restrict__ yg0,
    float* __restrict__ Yh, float* __restrict__ Ph, float* __restrict__ Nh)
{
  __shared__ __align__(16) f16 hfrag[8 * 64 * 8];   // [kt][lane][e], 8 KB
  const int tid = threadIdx.x;
  const int w = tid >> 6, l = tid & 63;
  const int cl = l & 15, lq = l >> 4;
  const int bid = blockIdx.x;
  const bool isY = (bid >= 128);
  int s = 0, f = 0, bh, slot;
  if (isY) { bh = bid & 1; slot = 64; }
  else { s = bid >> 6; f = (bid >> 1) & 31; bh = bid & 1; slot = s * 32 + f; }

  // U fragments -> registers (256 VGPRs/lane)
  f16x8 U[8][8];
  {
    const f16* ub = Uf + (size_t)slot * 262144 + (size_t)w * 32768 + (size_t)l * 8;
    #pragma unroll
    for (int nt = 0; nt < 8; ++nt)
      #pragma unroll
      for (int kt = 0; kt < 8; ++kt)
        U[nt][kt] = *(const f16x8*)(ub + (nt * 8 + kt) * 512);
  }

  float Wc[4][2], Bc[4][2];
  const float* Xsrc = nullptr;
  if (!isY) {
    const float* Wf = (s ? Wxn : Wxp) + (size_t)f * G4;
    const float* bf = (s ? bxn : bxp) + (size_t)f * G4;
    #pragma unroll
    for (int g = 0; g < 4; ++g)
      #pragma unroll
      for (int q = 0; q < 2; ++q) {
        const int col = g * 256 + w * 32 + q * 16 + cl;
        Wc[g][q] = Wf[col]; Bc[g][q] = bf[col];
      }
    Xsrc = s ? Xn : Xp;
  }
  float* Acc = s ? Nh : Ph;

  float c[2][4];
  #pragma unroll
  for (int q = 0; q < 2; ++q)
    #pragma unroll
    for (int j = 0; j < 4; ++j) c[q][j] = 0.f;

  *(uint4*)(hfrag + tid * 8) = uint4{0, 0, 0, 0};
  __syncthreads();

  for (int t = 0; t < T; ++t) {
    // A-fragments: h_prev (conflict-free b128 reads)
    f16x8 a8[8];
    #pragma unroll
    for (int kt = 0; kt < 8; ++kt)
      a8[kt] = *(const f16x8*)(hfrag + kt * 512 + l * 8);

    f32x4 acc[8];
    #pragma unroll
    for (int nt = 0; nt < 8; ++nt) acc[nt] = f32x4{0.f, 0.f, 0.f, 0.f};
    #pragma unroll
    for (int kt = 0; kt < 8; ++kt)
      #pragma unroll
      for (int nt = 0; nt < 8; ++nt)
        acc[nt] = __builtin_amdgcn_mfma_f32_16x16x32_f16(a8[kt], U[nt][kt], acc[nt], 0, 0, 0);

    float xin[4];
    if (!isY) {
      #pragma unroll
      for (int j = 0; j < 4; ++j)
        xin[j] = Xsrc[((size_t)(bh * 16 + lq * 4 + j) * T + t) * F + f];
    }
    __syncthreads();   // all waves done reading hfrag; safe to overwrite

    #pragma unroll
    for (int q = 0; q < 2; ++q) {
      const int ncol = w * 32 + q * 16 + cl;
      #pragma unroll
      for (int j = 0; j < 4; ++j) {
        const int b = bh * 16 + lq * 4 + j;
        float ip, fp, gp, op;
        if (isY) {
          const float* yrow = yg0 + ((size_t)b * T + t) * G4;
          ip = acc[0 + q][j] + yrow[0 * 256 + ncol];
          fp = acc[2 + q][j] + yrow[1 * 256 + ncol];
          gp = acc[4 + q][j] + yrow[2 * 256 + ncol];
          op = acc[6 + q][j] + yrow[3 * 256 + ncol];
        } else {
          ip = acc[0 + q][j] + xin[j] * Wc[0][q] + Bc[0][q];
          fp = acc[2 + q][j] + xin[j] * Wc[1][q] + Bc[1][q];
          gp = acc[4 + q][j] + xin[j] * Wc[2][q] + Bc[2][q];
          op = acc[6 + q][j] + xin[j] * Wc[3][q] + Bc[3][q];
        }
        const float ig = sigm(ip), fg = sigm(fp), gy = tanhf(gp), og = sigm(op);
        c[q][j] = fg * c[q][j] + ig * gy;
        const float h = og * tanhf(c[q][j]);
        const int dlane = (lq * 4 + j) + (q * 2 + (cl >> 3)) * 16;
        hfrag[w * 512 + dlane * 8 + (cl & 7)] = (f16)h;
        const size_t oidx = ((size_t)b * T + t) * H + ncol;
        if (isY) Yh[oidx] = h;
        else atomicAdd(&Acc[oidx], h * 0.03125f);
      }
    }
    __syncthreads();
  }
}

// ---------------------------------------------------------------------------
// k_xg: MI-LSTM input projections (unchanged from round 1).
// ---------------------------------------------------------------------------
__global__ __launch_bounds__(1024) void k_xg(
    const float* __restrict__ Yh, const float* __restrict__ Ph, const float* __restrict__ Nh,
    const float* __restrict__ Wm, const float* __restrict__ bm,
    const float* __restrict__ Wpa, const float* __restrict__ bpa,
    const float* __restrict__ Wna, const float* __restrict__ bna,
    float* __restrict__ yg, float* __restrict__ pg, float* __restrict__ ng)
{
  __shared__ __align__(16) float A[8][768];
  const int tid = threadIdx.x;
  const int ro  = blockIdx.x * 8;

  for (int idx = tid; idx < 8 * 768; idx += 1024) {
    const int r = idx / 768, cc = idx % 768;
    const int row = ro + r;
    float v;
    if (cc < 256)      v = Yh[(size_t)row * H + cc];
    else if (cc < 512) v = Ph[(size_t)row * H + (cc - 256)];
    else               v = Nh[(size_t)row * H + (cc - 512)];
    A[r][cc] = v;
  }
  __syncthreads();

  float acc[8];
  #pragma unroll
  for (int r = 0; r < 8; ++r) acc[r] = bm[tid];
  for (int k = 0; k < H; k += 4) {
    const float w0 = Wm[(k + 0) * G4 + tid];
    const float w1 = Wm[(k + 1) * G4 + tid];
    const float w2 = Wm[(k + 2) * G4 + tid];
    const float w3 = Wm[(k + 3) * G4 + tid];
    #pragma unroll
    for (int r = 0; r < 8; ++r) {
      const float4 av = *(const float4*)&A[r][k];
      acc[r] += w0 * av.x + w1 * av.y + w2 * av.z + w3 * av.w;
    }
  }
  #pragma unroll
  for (int r = 0; r < 8; ++r) yg[(size_t)(ro + r) * G4 + tid] = acc[r];

  const int col = tid & 511;
  const float* Wx = (tid < 512) ? Wpa : Wna;
  const float* bx = (tid < 512) ? bpa : bna;
  float* outp     = (tid < 512) ? pg : ng;
  const int aoff  = (tid < 512) ? 256 : 512;
  #pragma unroll
  for (int r = 0; r < 8; ++r) acc[r] = bx[col];
  for (int k = 0; k < H; k += 4) {
    const float w0 = Wx[(k + 0) * 512 + col];
    const float w1 = Wx[(k + 1) * 512 + col];
    const float w2 = Wx[(k + 2) * 512 + col];
    const float w3 = Wx[(k + 3) * 512 + col];
    #pragma unroll
    for (int r = 0; r < 8; ++r) {
      const float4 av = *(const float4*)&A[r][aoff + k];
      acc[r] += w0 * av.x + w1 * av.y + w2 * av.z + w3 * av.w;
    }
  }
  #pragma unroll
  for (int r = 0; r < 8; ++r) outp[(size_t)(ro + r) * 512 + col] = acc[r];
}

// ---------------------------------------------------------------------------
// k_mi: MI-LSTM scan, one block per batch element; weights now f16 (halves
// the per-CU L2 feed, the binding constraint).
// ---------------------------------------------------------------------------
__global__ __launch_bounds__(1024) void k_mi(
    const float* __restrict__ yg, const float* __restrict__ pg, const float* __restrict__ ng,
    const f16* __restrict__ Um, const f16* __restrict__ Upa, const f16* __restrict__ Una,
    const f16* __restrict__ Wa, const float* __restrict__ ba,
    float* __restrict__ Hm)
{
  __shared__ __align__(16) float h_lds[H];
  __shared__ __align__(16) float c_lds[H];
  __shared__ float g_lds[G4];
  __shared__ float ga_lds[G4];
  __shared__ float att_lds[H];
  __shared__ float red[3][4];
  const int tid = threadIdx.x;
  const int b   = blockIdx.x;

  if (tid < H) { h_lds[tid] = 0.f; c_lds[tid] = 0.f; }
  __syncthreads();

  for (int t = 0; t < T; ++t) {
    const size_t row = (size_t)b * T + t;

    float gacc = yg[row * G4 + tid];
    for (int k = 0; k < H; k += 4) {
      const float4 hv = *(const float4*)&h_lds[k];
      gacc += (float)Um[(k + 0) * G4 + tid] * hv.x + (float)Um[(k + 1) * G4 + tid] * hv.y
            + (float)Um[(k + 2) * G4 + tid] * hv.z + (float)Um[(k + 3) * G4 + tid] * hv.w;
    }

    const int acol = tid & 511;
    const f16* Ux = (tid < 512) ? Upa : Una;
    float aacc = (tid < 512) ? pg[row * 512 + acol] : ng[row * 512 + acol];
    for (int k = 0; k < H; k += 4) {
      const float4 hv = *(const float4*)&h_lds[k];
      aacc += (float)Ux[(k + 0) * 512 + acol] * hv.x + (float)Ux[(k + 1) * 512 + acol] * hv.y
            + (float)Ux[(k + 2) * 512 + acol] * hv.z + (float)Ux[(k + 3) * 512 + acol] * hv.w;
    }

    float attv = 0.f;
    if (tid < H) {
      attv = ba[tid];
      for (int k = 0; k < H; k += 4) {
        const float4 cv = *(const float4*)&c_lds[k];
        attv += (float)Wa[(k + 0) * H + tid] * cv.x + (float)Wa[(k + 1) * H + tid] * cv.y
              + (float)Wa[(k + 2) * H + tid] * cv.z + (float)Wa[(k + 3) * H + tid] * cv.w;
      }
      attv = tanhf(attv);
    }

    g_lds[tid]  = gacc;
    ga_lds[tid] = aacc;
    if (tid < H) att_lds[tid] = attv;
    __syncthreads();

    float l0 = 0.f, l1 = 0.f, l2 = 0.f, fg = 0.f, og = 0.f;
    if (tid < H) {
      const int n = tid;
      const float ig = sigm(g_lds[n]);
      fg = sigm(g_lds[H + n]);
      const float gy = tanhf(g_lds[2 * H + n]);
      og = sigm(g_lds[3 * H + n]);
      l0 = ig * gy;
      l1 = sigm(ga_lds[n])         * tanhf(ga_lds[H + n]);
      l2 = sigm(ga_lds[2 * H + n]) * tanhf(ga_lds[3 * H + n]);
      const float a = att_lds[n];
      float v0 = l0 * a, v1 = l1 * a, v2 = l2 * a;
      for (int off = 32; off; off >>= 1) {
        v0 += __shfl_down(v0, off);
        v1 += __shfl_down(v1, off);
        v2 += __shfl_down(v2, off);
      }
      if ((tid & 63) == 0) {
        red[0][tid >> 6] = v0; red[1][tid >> 6] = v1; red[2][tid >> 6] = v2;
      }
    }
    __syncthreads();

    if (tid < H) {
      const int n = tid;
      const float s0 = red[0][0] + red[0][1] + red[0][2] + red[0][3];
      const float s1 = red[1][0] + red[1][1] + red[1][2] + red[1][3];
      const float s2 = red[2][0] + red[2][1] + red[2][2] + red[2][3];
      const float m  = fmaxf(s0, fmaxf(s1, s2));
      const float e0 = expf(s0 - m), e1 = expf(s1 - m), e2 = expf(s2 - m);
      const float inv = 1.f / (e0 + e1 + e2);
      const float lt  = (e0 * l0 + e1 * l1 + e2 * l2) * inv;
      const float cc  = fg * c_lds[n] + lt;
      const float h   = og * tanhf(cc);
      c_lds[n] = cc;
      h_lds[n] = h;
      Hm[row * H + n] = h;
    }
    __syncthreads();
  }
}

// ---------------------------------------------------------------------------
// k_att: temporal additive attention + linear head (unchanged).
// ---------------------------------------------------------------------------
__global__ __launch_bounds__(256) void k_att(
    const float* __restrict__ Hm, const float* __restrict__ Watt, const float* __restrict__ batt,
    const float* __restrict__ vatt, const float* __restrict__ Wlin, const float* __restrict__ blin,
    float* __restrict__ out)
{
  __shared__ __align__(16) float hm8[8][H];
  __shared__ float vred[8][4];
  __shared__ float s_lds[T];
  __shared__ float alpha_lds[T];
  __shared__ float red4[4];
  const int n = threadIdx.x;
  const int b = blockIdx.x;
  const float bn = batt[n], vn = vatt[n];

  for (int t0 = 0; t0 < T; t0 += 8) {
    __syncthreads();
    #pragma unroll
    for (int r = 0; r < 8; ++r) hm8[r][n] = Hm[((size_t)b * T + t0 + r) * H + n];
    __syncthreads();
    float acc[8];
    #pragma unroll
    for (int r = 0; r < 8; ++r) acc[r] = bn;
    for (int k = 0; k < H; k += 4) {
      const float w0 = Watt[(k + 0) * H + n];
      const float w1 = Watt[(k + 1) * H + n];
      const float w2 = Watt[(k + 2) * H + n];
      const float w3 = Watt[(k + 3) * H + n];
      #pragma unroll
      for (int r = 0; r < 8; ++r) {
        const float4 hv = *(const float4*)&hm8[r][k];
        acc[r] += w0 * hv.x + w1 * hv.y + w2 * hv.z + w3 * hv.w;
      }
    }
    #pragma unroll
    for (int r = 0; r < 8; ++r) {
      float v = tanhf(acc[r]) * vn;
      for (int off = 32; off; off >>= 1) v += __shfl_down(v, off);
      if ((n & 63) == 0) vred[r][n >> 6] = v;
    }
    __syncthreads();
    if (n < 8) s_lds[t0 + n] = vred[n][0] + vred[n][1] + vred[n][2] + vred[n][3];
  }
  __syncthreads();

  if (n < T) {
    const float sv = s_lds[n];
    float m = sv;
    for (int off = 32; off; off >>= 1) m = fmaxf(m, __shfl_xor(m, off));
    const float e = expf(sv - m);
    float sum = e;
    for (int off = 32; off; off >>= 1) sum += __shfl_xor(sum, off);
    alpha_lds[n] = e / sum;
  }
  __syncthreads();

  float acc = 0.f;
  for (int t = 0; t < T; ++t) acc += alpha_lds[t] * Hm[((size_t)b * T + t) * H + n];
  float p = acc * Wlin[n];
  for (int off = 32; off; off >>= 1) p += __shfl_down(p, off);
  if ((n & 63) == 0) red4[n >> 6] = p;
  __syncthreads();
  if (n == 0) out[b] = fmaxf(red4[0] + red4[1] + red4[2] + red4[3] + blin[0], 0.f);
}

// ---------------------------------------------------------------------------
extern "C" void kernel_launch(void* const* d_in, const int* in_sizes, int n_in,
                              void* d_out, int out_size, void* d_ws, size_t ws_size,
                              hipStream_t stream) {
  const float* Yin  = (const float*)d_in[0];
  const float* Xp   = (const float*)d_in[1];
  const float* Xn   = (const float*)d_in[2];
  const float* Wy   = (const float*)d_in[3];
  const float* Uy   = (const float*)d_in[4];
  const float* by   = (const float*)d_in[5];
  const float* Wxp  = (const float*)d_in[6];
  const float* Uxp  = (const float*)d_in[7];
  const float* bxp  = (const float*)d_in[8];
  const float* Wxn  = (const float*)d_in[9];
  const float* Uxn  = (const float*)d_in[10];
  const float* bxn  = (const float*)d_in[11];
  const float* Wm   = (const float*)d_in[12];
  const float* Um   = (const float*)d_in[13];
  const float* bm   = (const float*)d_in[14];
  const float* Wpa  = (const float*)d_in[15];
  const float* Upa  = (const float*)d_in[16];
  const float* bpa  = (const float*)d_in[17];
  const float* Wna  = (const float*)d_in[18];
  const float* Una  = (const float*)d_in[19];
  const float* bna  = (const float*)d_in[20];
  const float* Wa   = (const float*)d_in[21];
  const float* ba   = (const float*)d_in[22];
  const float* Watt = (const float*)d_in[23];
  const float* batt = (const float*)d_in[24];
  const float* vatt = (const float*)d_in[25];
  const float* Wlin = (const float*)d_in[26];
  const float* blin = (const float*)d_in[27];

  float* ws = (float*)d_ws;
  float* Yh  = ws;                  // 524288
  float* Ph  = ws + 524288;         // 524288
  float* Nh  = ws + 1048576;        // 524288
  float* Hm  = ws + 1572864;        // 524288
  float* yg  = ws + 2097152;        // 2097152
  float* pg  = ws + 4194304;        // 1048576
  float* ng  = ws + 5242880;        // 1048576
  float* yg0 = ws + 6291456;        // 2097152
  f16*   Uf  = (f16*)(ws + 8388608);    // 65*262144 f16 = 8519680 floats
  f16*   Umh = (f16*)(ws + 16908288);   // 262144 f16
  f16*   Uph = (f16*)(ws + 17039360);   // 131072 f16
  f16*   Unh = (f16*)(ws + 17104896);   // 131072 f16
  f16*   Wah = (f16*)(ws + 17170432);   // 65536 f16
  float* out = (float*)d_out;

  hipMemsetAsync(Ph, 0, (size_t)2 * 524288 * sizeof(float), stream);

  k_prep_u  <<<65, 512, 0, stream>>>(Uxp, Uxn, Uy, Uf);
  k_prep_w  <<<256, 1024, 0, stream>>>(Um, Upa, Una, Wa, Umh, Uph, Unh, Wah);
  k_prep_yg0<<<128, 1024, 0, stream>>>(Yin, Wy, by, yg0);

  k_scan<<<130, 512, 0, stream>>>(Xp, Xn, Wxp, bxp, Wxn, bxn, Uf, yg0, Yh, Ph, Nh);
  k_xg  <<<256, 1024, 0, stream>>>(Yh, Ph, Nh, Wm, bm, Wpa, bpa, Wna, bna, yg, pg, ng);
  k_mi  <<<32, 1024, 0, stream>>>(yg, pg, ng, Umh, Uph, Unh, Wah, ba, Hm);
  k_att <<<32, 256, 0, stream>>>(Hm, Watt, batt, vatt, Wlin, blin, out);
}